// Round 9
// baseline (290.242 us; speedup 1.0000x reference)
//
#include <hip/hip_runtime.h>
#include <math.h>

#define D_MODEL 1024
#define D_STATE 8
#define D_CONV  4
#define D_INNER 1536
#define DT_RANK 64
#define D_FF    2048
#define BATCH   2
#define SEQ     2048
#define NROWS   (BATCH*SEQ)      // 4096
#define NC      32               // scan chunks
#define LC      (SEQ/NC)         // 64
#define XPAD    128              // padded x_dbl width (was 80)

typedef short bf16x8 __attribute__((ext_vector_type(8)));
typedef unsigned short u16x8 __attribute__((ext_vector_type(8)));
typedef float f32x4  __attribute__((ext_vector_type(4)));

__device__ inline unsigned short f2bf(float x) {
    union { float f; unsigned u; } v; v.f = x;
    unsigned r = v.u + 0x7fffu + ((v.u >> 16) & 1u);
    return (unsigned short)(r >> 16);
}
__device__ inline float bf2f(unsigned short h) {
    union { unsigned u; float f; } v; v.u = ((unsigned)h) << 16;
    return v.f;
}
__device__ inline float softplus_f(float x) {
    return (x > 20.0f) ? x : log1pf(__expf(x));
}
__device__ inline float gelu_f(float x) {
    return 0.5f * x * (1.0f + erff(x * 0.70710678118654752f));
}
__device__ inline float silu_f(float x) {
    return x / (1.0f + __expf(-x));
}
__device__ inline void gload16(const unsigned short* g, unsigned short* l) {
    typedef unsigned int u32;
    __builtin_amdgcn_global_load_lds(
        (const __attribute__((address_space(1))) u32*)g,
        (__attribute__((address_space(3))) u32*)l, 16, 0, 0);
}

#define PHASE_SYNC_PRE()  do { __builtin_amdgcn_s_barrier(); \
                               asm volatile("s_waitcnt lgkmcnt(0)" ::: "memory"); } while (0)
#define PHASE_SYNC_POST() do { __builtin_amdgcn_s_barrier(); } while (0)

// ---------------- prep mega-kernel: weight conv + xproj pad + LN1 ----------------
__global__ __launch_bounds__(256) void prep_kernel(
    const float* __restrict__ s0, unsigned short* __restrict__ d0,
    const float* __restrict__ s1, unsigned short* __restrict__ d1,
    const float* __restrict__ s2, unsigned short* __restrict__ d2,
    const float* __restrict__ s3, unsigned short* __restrict__ d3,
    const float* __restrict__ s4, unsigned short* __restrict__ d4,
    const float* __restrict__ xpw, unsigned short* __restrict__ xpd,
    const float* __restrict__ x, const float* __restrict__ g1,
    const float* __restrict__ b1, unsigned short* __restrict__ xout) {
    int b = blockIdx.x;
    if (b < 4400) {
        const float* s; unsigned short* d; int base;
        if      (b < 1536) { s = s0; d = d0; base = b * 2048; }
        else if (b < 1584) { s = s1; d = d1; base = (b - 1536) * 2048; }
        else if (b < 2352) { s = s2; d = d2; base = (b - 1584) * 2048; }
        else if (b < 3376) { s = s3; d = d3; base = (b - 2352) * 2048; }
        else               { s = s4; d = d4; base = (b - 3376) * 2048; }
        int i = base + threadIdx.x * 8;
        float4 v0 = *(const float4*)(s + i);
        float4 v1 = *(const float4*)(s + i + 4);
        ushort4 a, c;
        a.x = f2bf(v0.x); a.y = f2bf(v0.y); a.z = f2bf(v0.z); a.w = f2bf(v0.w);
        c.x = f2bf(v1.x); c.y = f2bf(v1.y); c.z = f2bf(v1.z); c.w = f2bf(v1.w);
        *(ushort4*)(d + i)     = a;
        *(ushort4*)(d + i + 4) = c;
    } else if (b < 4528) {
        int row = b - 4400;
        for (int c = threadIdx.x; c < D_INNER; c += 256)
            xpd[row * D_INNER + c] = (row < 80) ? f2bf(xpw[row * D_INNER + c]) : (unsigned short)0;
    } else {
        __shared__ float sbuf[4];
        int row = b - 4528;
        int t = threadIdx.x;
        float4 v = ((const float4*)(x + (size_t)row * D_MODEL))[t];
        float s = v.x + v.y + v.z + v.w;
        for (int o = 32; o; o >>= 1) s += __shfl_down(s, o, 64);
        if ((t & 63) == 0) sbuf[t >> 6] = s;
        __syncthreads();
        float mu = (sbuf[0] + sbuf[1] + sbuf[2] + sbuf[3]) * (1.0f / D_MODEL);
        __syncthreads();
        float e0 = v.x - mu, e1 = v.y - mu, e2 = v.z - mu, e3 = v.w - mu;
        float q = e0*e0 + e1*e1 + e2*e2 + e3*e3;
        for (int o = 32; o; o >>= 1) q += __shfl_down(q, o, 64);
        if ((t & 63) == 0) sbuf[t >> 6] = q;
        __syncthreads();
        float var = (sbuf[0] + sbuf[1] + sbuf[2] + sbuf[3]) * (1.0f / D_MODEL);
        float rs = rsqrtf(var + 1e-5f);
        float4 gv = ((const float4*)g1)[t];
        float4 bv = ((const float4*)b1)[t];
        ushort4 st;
        st.x = f2bf(e0 * rs * gv.x + bv.x);
        st.y = f2bf(e1 * rs * gv.y + bv.y);
        st.z = f2bf(e2 * rs * gv.z + bv.z);
        st.w = f2bf(e3 * rs * gv.w + bv.w);
        ((ushort4*)(xout + (size_t)row * D_MODEL))[t] = st;
    }
}

// ---------------- LayerNorm -> bf16 ----------------
__global__ __launch_bounds__(256) void ln_kernel(const float* __restrict__ x,
                                                 const float* __restrict__ g,
                                                 const float* __restrict__ b,
                                                 unsigned short* __restrict__ out) {
    __shared__ float sbuf[4];
    int row = blockIdx.x;
    int t = threadIdx.x;
    float4 v = ((const float4*)(x + (size_t)row * D_MODEL))[t];
    float s = v.x + v.y + v.z + v.w;
    for (int o = 32; o; o >>= 1) s += __shfl_down(s, o, 64);
    if ((t & 63) == 0) sbuf[t >> 6] = s;
    __syncthreads();
    float mu = (sbuf[0] + sbuf[1] + sbuf[2] + sbuf[3]) * (1.0f / D_MODEL);
    __syncthreads();
    float d0 = v.x - mu, d1 = v.y - mu, d2 = v.z - mu, d3 = v.w - mu;
    float q = d0*d0 + d1*d1 + d2*d2 + d3*d3;
    for (int o = 32; o; o >>= 1) q += __shfl_down(q, o, 64);
    if ((t & 63) == 0) sbuf[t >> 6] = q;
    __syncthreads();
    float var = (sbuf[0] + sbuf[1] + sbuf[2] + sbuf[3]) * (1.0f / D_MODEL);
    float rs = rsqrtf(var + 1e-5f);
    float4 gv = ((const float4*)g)[t];
    float4 bv = ((const float4*)b)[t];
    ushort4 st;
    st.x = f2bf(d0 * rs * gv.x + bv.x);
    st.y = f2bf(d1 * rs * gv.y + bv.y);
    st.z = f2bf(d2 * rs * gv.z + bv.z);
    st.w = f2bf(d3 * rs * gv.w + bv.w);
    ((ushort4*)(out + (size_t)row * D_MODEL))[t] = st;
}

// ---------------- epilogue IDs ----------------
#define EPI_F32        0
#define EPI_BF16       6
#define EPI_SCR        8   // scrambled bf16 partials (coalesced), WN==4 only
#define EPI_SOFTPLUS_BF16 7

// ================= 8-phase 256-row MFMA GEMM (NT) =================
template<int WN, int EPI, int SPLITK>
__global__ __launch_bounds__(512, 2) void gemm8p(
    const unsigned short* __restrict__ A, int lda,
    const unsigned short* __restrict__ Bm, int ldb, int K,
    float* __restrict__ Cf, unsigned short* __restrict__ Cb, int ldc,
    const float* __restrict__ bias,
    const float* __restrict__ resid, int ldr) {
    constexpr int WM = 8 / WN;
    constexpr int BN = WN * 64;
    constexpr int RW = 256 / WM;
    constexpr int CW = 64;
    constexpr int MI = RW / 16;
    constexpr int NI = CW / 16;
    constexpr int MIH = MI / 2, NIH = NI / 2;
    constexpr int ABYTES = 256 * 128;
    constexpr int BBYTES = BN * 128;
    constexpr int BOFF = 2 * ABYTES;
    __shared__ unsigned short lds[(2 * ABYTES + 2 * BBYTES) / 2];

    const int t = threadIdx.x, l = t & 63, w = t >> 6;
    const int wr = w / WN, wc = w % WN;

    const int nx = gridDim.x;
    const int nwg = nx * gridDim.y;
    int bid = blockIdx.y * nx + blockIdx.x;
    int q = nwg >> 3;
    int swz = (bid & 7) * q + (bid >> 3);
    const int m0 = (swz / nx) * 256, n0 = (swz % nx) * BN;
    const int kbase = (SPLITK > 1) ? blockIdx.z * K : 0;

    // involution swizzle: LDS[r][byte] = G[r][byte ^ ((r&7)<<4)]
    const int sr = l >> 3;
    const int sj = ((l & 7) * 16) ^ ((l >> 3) << 4);
    const int row_l = w * 8;
    const int row_c = (w >> 2) * 64 + (w & 3) * 8;

    auto STG = [&](int bufbyte, int rowbase, const unsigned short* G, int ldg, int gbase, int kt) {
        unsigned short* dst = (unsigned short*)((char*)lds + bufbyte + rowbase * 128);
        const unsigned short* src = G + (size_t)(gbase + rowbase + sr) * ldg + kbase + kt * 64 + (sj >> 1);
        gload16(src, dst);
    };
    auto S_Ah0 = [&](int b, int kt) {
        if (WN == 4) { STG(b * ABYTES, row_l, A, lda, m0, kt);       STG(b * ABYTES, 128 + row_l, A, lda, m0, kt); }
        else         { STG(b * ABYTES, row_c, A, lda, m0, kt);       STG(b * ABYTES, 128 + row_c, A, lda, m0, kt); }
    };
    auto S_Ah1 = [&](int b, int kt) {
        if (WN == 4) { STG(b * ABYTES, 64 + row_l, A, lda, m0, kt);  STG(b * ABYTES, 192 + row_l, A, lda, m0, kt); }
        else         { STG(b * ABYTES, 32 + row_c, A, lda, m0, kt);  STG(b * ABYTES, 160 + row_c, A, lda, m0, kt); }
    };
    auto S_Bc0 = [&](int b, int kt) {
        if (WN == 4) { STG(BOFF + b * BBYTES, row_c, Bm, ldb, n0, kt); STG(BOFF + b * BBYTES, 128 + row_c, Bm, ldb, n0, kt); }
        else         { STG(BOFF + b * BBYTES, row_c, Bm, ldb, n0, kt); }
    };
    auto S_Bc1 = [&](int b, int kt) {
        if (WN == 4) { STG(BOFF + b * BBYTES, 32 + row_c, Bm, ldb, n0, kt); STG(BOFF + b * BBYTES, 160 + row_c, Bm, ldb, n0, kt); }
        else         { STG(BOFF + b * BBYTES, 32 + row_c, Bm, ldb, n0, kt); }
    };

    auto LD = [&](int bytebase, int row, int kb) -> bf16x8 {
        int o = bytebase + row * 128 + (kb ^ ((row & 7) << 4));
        return *(const bf16x8*)((const char*)lds + o);
    };

    f32x4 acc[MI][NI] = {};
    bf16x8 af[MIH][2], b0v[NIH][2], b1v[NIH][2];

    auto LDA_set = [&](int buf, int qr, auto& dst) {
        #pragma unroll
        for (int mi = 0; mi < MIH; mi++)
            #pragma unroll
            for (int ks = 0; ks < 2; ks++)
                dst[mi][ks] = LD(buf * ABYTES, wr * RW + qr * (RW / 2) + mi * 16 + (l & 15),
                                 ks * 64 + (l >> 4) * 16);
    };
    auto LDB_set = [&](int buf, int qc, auto& dst) {
        #pragma unroll
        for (int ni2 = 0; ni2 < NIH; ni2++)
            #pragma unroll
            for (int ks = 0; ks < 2; ks++)
                dst[ni2][ks] = LD(BOFF + buf * BBYTES, wc * CW + qc * 32 + ni2 * 16 + (l & 15),
                                  ks * 64 + (l >> 4) * 16);
    };
    auto MFMA_Q = [&](int qr, int qc, auto& a_, auto& b_) {
        __builtin_amdgcn_s_setprio(1);
        #pragma unroll
        for (int mi = 0; mi < MIH; mi++)
            #pragma unroll
            for (int ni2 = 0; ni2 < NIH; ni2++)
                #pragma unroll
                for (int ks = 0; ks < 2; ks++)
                    acc[qr * MIH + mi][qc * NIH + ni2] =
                        __builtin_amdgcn_mfma_f32_16x16x32_bf16(a_[mi][ks], b_[ni2][ks],
                                                                acc[qr * MIH + mi][qc * NIH + ni2], 0, 0, 0);
        __builtin_amdgcn_s_setprio(0);
    };
    auto VMW = [&](bool last) {
        if (last)            asm volatile("s_waitcnt vmcnt(0)" ::: "memory");
        else if (WN == 4)    asm volatile("s_waitcnt vmcnt(6)" ::: "memory");
        else                 asm volatile("s_waitcnt vmcnt(5)" ::: "memory");
    };

    const int ni_ = K >> 7;

    S_Ah0(0, 0); S_Ah1(0, 0); S_Bc0(0, 0); S_Bc1(0, 0);
    S_Ah0(1, 1); S_Ah1(1, 1); S_Bc0(1, 1); S_Bc1(1, 1);
    if (WN == 4) asm volatile("s_waitcnt vmcnt(8)" ::: "memory");
    else         asm volatile("s_waitcnt vmcnt(6)" ::: "memory");
    __builtin_amdgcn_s_barrier();

    for (int i = 0; i < ni_; i++) {
        const bool last = (i == ni_ - 1);
        const int t2 = 2 * i + 2, t3 = 2 * i + 3;
        // phase 1
        LDA_set(0, 0, af); LDB_set(0, 0, b0v);
        if (i) S_Bc0(1, 2 * i + 1);
        PHASE_SYNC_PRE(); MFMA_Q(0, 0, af, b0v); PHASE_SYNC_POST();
        // phase 2
        LDB_set(0, 1, b1v);
        if (!last) S_Ah0(0, t2);
        PHASE_SYNC_PRE(); MFMA_Q(0, 1, af, b1v); PHASE_SYNC_POST();
        // phase 3
        LDA_set(0, 1, af);
        PHASE_SYNC_PRE(); MFMA_Q(1, 1, af, b1v); PHASE_SYNC_POST();
        // phase 4
        LDB_set(0, 0, b0v);
        if (!last) { S_Ah1(0, t2); S_Bc1(0, t2); }
        VMW(last);
        PHASE_SYNC_PRE(); MFMA_Q(1, 0, af, b0v); PHASE_SYNC_POST();
        // phase 5
        LDA_set(1, 0, af); LDB_set(1, 0, b0v);
        if (!last) S_Bc0(0, t2);
        PHASE_SYNC_PRE(); MFMA_Q(0, 0, af, b0v); PHASE_SYNC_POST();
        // phase 6
        LDB_set(1, 1, b1v);
        if (!last) S_Ah0(1, t3);
        PHASE_SYNC_PRE(); MFMA_Q(0, 1, af, b1v); PHASE_SYNC_POST();
        // phase 7
        LDA_set(1, 1, af);
        PHASE_SYNC_PRE(); MFMA_Q(1, 1, af, b1v); PHASE_SYNC_POST();
        // phase 8
        LDB_set(1, 0, b0v);
        if (!last) { S_Ah1(1, t3); S_Bc1(1, t3); }
        VMW(last);
        PHASE_SYNC_PRE(); MFMA_Q(1, 0, af, b0v); PHASE_SYNC_POST();
    }

    if (EPI == EPI_SCR) {
        // scrambled coalesced bf16 partial dump: chunk=swz (65536 shorts),
        // wave 8192, frag(mi*4+ni2) 256, lane 4 shorts. Per-wave 512B contiguous.
        unsigned short* ps = Cb + (size_t)blockIdx.z * ((size_t)nwg * 65536);
        size_t base = (size_t)swz * 65536 + w * 8192 + l * 4;
        #pragma unroll
        for (int mi = 0; mi < MI; mi++)
            #pragma unroll
            for (int ni2 = 0; ni2 < NI; ni2++) {
                ushort4 pk;
                pk.x = f2bf(acc[mi][ni2][0]);
                pk.y = f2bf(acc[mi][ni2][1]);
                pk.z = f2bf(acc[mi][ni2][2]);
                pk.w = f2bf(acc[mi][ni2][3]);
                *(ushort4*)(ps + base + (mi * 4 + ni2) * 256) = pk;
            }
        return;
    }

    float* Cfp = Cf;
    if (SPLITK > 1) Cfp += (size_t)blockIdx.z * NROWS * ldc;
    #pragma unroll
    for (int ni2 = 0; ni2 < NI; ni2++) {
        int col = n0 + wc * CW + ni2 * 16 + (l & 15);
        #pragma unroll
        for (int mi = 0; mi < MI; mi++) {
            #pragma unroll
            for (int j = 0; j < 4; j++) {
                int row = m0 + wr * RW + mi * 16 + (l >> 4) * 4 + j;
                float v = acc[mi][ni2][j];
                if (EPI == EPI_BF16) {
                    Cb[(size_t)row * ldc + col] = f2bf(v);
                } else {
                    Cfp[(size_t)row * ldc + col] = v;
                }
            }
        }
    }
}

// ---------------- scrambled split-K reduce; MODE 0: 4sp+resid->f32
//                  MODE 1: 2sp+bias+gelu->bf16   MODE 2: 4sp+bias+resid->f32
template<int MODE>
__global__ __launch_bounds__(256) void skscr(const unsigned short* __restrict__ ps,
                                             const float* __restrict__ bias,
                                             const float* __restrict__ resid,
                                             float* __restrict__ of,
                                             unsigned short* __restrict__ ob,
                                             int nchunks, int N) {
    int tid = blockIdx.x * 256 + threadIdx.x;   // one f32x4 position (4 rows, 1 col)
    int c = tid >> 14;
    int r = tid & 16383;
    int w = r >> 11;
    int f = (r >> 6) & 31;
    int l = r & 63;
    int mi = f >> 2, ni2 = f & 3;
    int nx = N >> 8;
    int m0 = (c / nx) << 8, n0 = (c % nx) << 8;
    int row = m0 + ((w >> 2) << 7) + mi * 16 + ((l >> 4) << 2);
    int col = n0 + ((w & 3) << 6) + ni2 * 16 + (l & 15);
    size_t off = (size_t)c * 65536 + w * 8192 + f * 256 + l * 4;
    size_t seg = (size_t)nchunks * 65536;
    ushort4 a0 = *(const ushort4*)(ps + off);
    ushort4 a1 = *(const ushort4*)(ps + off + seg);
    float v0 = bf2f(a0.x) + bf2f(a1.x);
    float v1 = bf2f(a0.y) + bf2f(a1.y);
    float v2 = bf2f(a0.z) + bf2f(a1.z);
    float v3 = bf2f(a0.w) + bf2f(a1.w);
    if (MODE != 1) {
        ushort4 a2 = *(const ushort4*)(ps + off + 2 * seg);
        ushort4 a3 = *(const ushort4*)(ps + off + 3 * seg);
        v0 += bf2f(a2.x) + bf2f(a3.x);
        v1 += bf2f(a2.y) + bf2f(a3.y);
        v2 += bf2f(a2.z) + bf2f(a3.z);
        v3 += bf2f(a2.w) + bf2f(a3.w);
    }
    float bv = (MODE != 0) ? bias[col] : 0.0f;
    float vv[4] = {v0, v1, v2, v3};
    #pragma unroll
    for (int j = 0; j < 4; j++) {
        size_t o = (size_t)(row + j) * N + col;
        if (MODE == 1) {
            ob[o] = f2bf(gelu_f(vv[j] + bv));
        } else if (MODE == 0) {
            of[o] = vv[j] + resid[o];
        } else {
            of[o] = vv[j] + bv + resid[o];
        }
    }
}

// ---------------- small-GEMM path (x_proj, dt_proj): 128x128, 3-buf ----------------
template<int EPI, int SPLITK>
__global__ __launch_bounds__(256) void gemm_mfma(
    const unsigned short* __restrict__ A, int lda,
    const unsigned short* __restrict__ B, int ldb, int K,
    float* __restrict__ Cf, unsigned short* __restrict__ Cb, int ldc,
    const float* __restrict__ bias,
    const float* __restrict__ resid, int ldr) {
    __shared__ unsigned short As[3][128 * 32];
    __shared__ unsigned short Bs[3][128 * 32];
    int t = threadIdx.x, l = t & 63, w = t >> 6;
    int nx = gridDim.x;
    int nwg = nx * gridDim.y;
    int bid = blockIdx.y * nx + blockIdx.x;
    int q = nwg >> 3;
    int swz = (bid & 7) * q + (bid >> 3);
    int m0 = (swz / nx) * 128, n0 = (swz % nx) * 128;
    int kbase = (SPLITK > 1) ? blockIdx.z * K : 0;
    int c0 = 2 * w, c1 = 2 * w + 1;
    int srow = l >> 2, scol = (l & 3) * 8;
    const unsigned short* Ag0 = A + (size_t)(m0 + 16 * c0 + srow) * lda + kbase + scol;
    const unsigned short* Ag1 = A + (size_t)(m0 + 16 * c1 + srow) * lda + kbase + scol;
    const unsigned short* Bg0 = B + (size_t)(n0 + 16 * c0 + srow) * ldb + kbase + scol;
    const unsigned short* Bg1 = B + (size_t)(n0 + 16 * c1 + srow) * ldb + kbase + scol;
    int wr = w >> 1, wc = w & 1;
    int aoff = (wr * 64 + (l & 15)) * 32 + (l >> 4) * 8;
    int boff = (wc * 64 + (l & 15)) * 32 + (l >> 4) * 8;

    f32x4 acc[4][4] = {};
    int nt = K >> 5;

    gload16(Ag0, &As[0][c0 * 512]);
    gload16(Ag1, &As[0][c1 * 512]);
    gload16(Bg0, &Bs[0][c0 * 512]);
    gload16(Bg1, &Bs[0][c1 * 512]);
    if (nt > 1) {
        gload16(Ag0 + 32, &As[1][c0 * 512]);
        gload16(Ag1 + 32, &As[1][c1 * 512]);
        gload16(Bg0 + 32, &Bs[1][c0 * 512]);
        gload16(Bg1 + 32, &Bs[1][c1 * 512]);
    }

    int cur = 0;
    for (int ti = 0; ti < nt; ti++) {
        int pf = ti + 2;
        if (pf < nt) {
            int nb = cur - 1; if (nb < 0) nb += 3;
            int k0 = pf << 5;
            gload16(Ag0 + k0, &As[nb][c0 * 512]);
            gload16(Ag1 + k0, &As[nb][c1 * 512]);
            gload16(Bg0 + k0, &Bs[nb][c0 * 512]);
            gload16(Bg1 + k0, &Bs[nb][c1 * 512]);
        }
        int rem = nt - 1 - ti;
        if (rem >= 2)      asm volatile("s_waitcnt vmcnt(8)" ::: "memory");
        else if (rem == 1) asm volatile("s_waitcnt vmcnt(4)" ::: "memory");
        else               asm volatile("s_waitcnt vmcnt(0)" ::: "memory");
        __builtin_amdgcn_s_barrier();

        const unsigned short* Ab = &As[cur][0];
        const unsigned short* Bb = &Bs[cur][0];
        bf16x8 af[4], bfv[4];
        #pragma unroll
        for (int i = 0; i < 4; i++) af[i] = *(const bf16x8*)(Ab + aoff + i * 512);
        #pragma unroll
        for (int i = 0; i < 4; i++) bfv[i] = *(const bf16x8*)(Bb + boff + i * 512);
        __builtin_amdgcn_s_setprio(1);
        #pragma unroll
        for (int mi = 0; mi < 4; mi++)
            #pragma unroll
            for (int ni = 0; ni < 4; ni++)
                acc[mi][ni] = __builtin_amdgcn_mfma_f32_16x16x32_bf16(af[mi], bfv[ni], acc[mi][ni], 0, 0, 0);
        __builtin_amdgcn_s_setprio(0);
        __builtin_amdgcn_s_barrier();
        cur++; if (cur == 3) cur = 0;
    }

    if (SPLITK > 1) Cf += (size_t)blockIdx.z * NROWS * ldc;
    int colb = n0 + wc * 64 + (l & 15);
    int rowb = m0 + wr * 64 + (l >> 4) * 4;
    #pragma unroll
    for (int ni = 0; ni < 4; ni++) {
        int col = colb + ni * 16;
        float bv = 0.0f;
        if (EPI == EPI_SOFTPLUS_BF16) bv = bias[col];
        #pragma unroll
        for (int mi = 0; mi < 4; mi++) {
            #pragma unroll
            for (int j = 0; j < 4; j++) {
                int row = rowb + mi * 16 + j;
                float v = acc[mi][ni][j];
                if (EPI == EPI_SOFTPLUS_BF16) v = softplus_f(v + bv);
                if (EPI == EPI_BF16 || EPI == EPI_SOFTPLUS_BF16) {
                    Cb[(size_t)row * ldc + col] = f2bf(v);
                } else {
                    Cf[(size_t)row * ldc + col] = v;
                }
            }
        }
    }
}

// ---------------- x_proj split-K partial reduce ----------------
__global__ __launch_bounds__(256) void xdbl_reduce(const float* __restrict__ part,
                                                   float* __restrict__ xdbl,
                                                   unsigned short* __restrict__ xdbl_bf) {
    int i = blockIdx.x * 256 + threadIdx.x;
    const size_t seg = (size_t)NROWS * XPAD;
    float s = part[i] + part[i + seg] + part[i + 2 * seg] + part[i + 3 * seg];
    xdbl[i] = s;
    xdbl_bf[i] = f2bf(s);
}

// ---------------- causal depthwise conv (k=4) + SiLU -> bf16 u (8-wide) ----------------
__global__ __launch_bounds__(256) void conv_silu(const unsigned short* __restrict__ xz,
                                                 const float* __restrict__ w,
                                                 const float* __restrict__ cb,
                                                 unsigned short* __restrict__ u) {
    int idx = (blockIdx.x * 256 + threadIdx.x) * 8;
    int d = idx % D_INNER;
    int bl = idx / D_INNER;
    int l = bl & (SEQ - 1);
    float acc[8];
    float4 wv[8];
    #pragma unroll
    for (int j = 0; j < 8; j++) wv[j] = *(const float4*)(w + (d + j) * 4);
    float4 cb0 = *(const float4*)(cb + d);
    float4 cb1 = *(const float4*)(cb + d + 4);
    acc[0] = cb0.x; acc[1] = cb0.y; acc[2] = cb0.z; acc[3] = cb0.w;
    acc[4] = cb1.x; acc[5] = cb1.y; acc[6] = cb1.z; acc[7] = cb1.w;
    #pragma unroll
    for (int k = 0; k < 4; k++) {
        int lp = l - 3 + k;
        if (lp >= 0) {
            u16x8 s = *(const u16x8*)(xz + (size_t)(bl - 3 + k) * (2 * D_INNER) + d);
            #pragma unroll
            for (int j = 0; j < 8; j++) {
                float wk = (k == 0) ? wv[j].x : (k == 1) ? wv[j].y : (k == 2) ? wv[j].z : wv[j].w;
                acc[j] += bf2f((unsigned short)s[j]) * wk;
            }
        }
    }
    u16x8 o;
    #pragma unroll
    for (int j = 0; j < 8; j++) o[j] = f2bf(silu_f(acc[j]));
    *(u16x8*)(u + idx) = o;
}

// ---------------- selective scan: pass A ----------------
__global__ __launch_bounds__(256) void scan_passA(const unsigned short* __restrict__ delta,
                                                  const unsigned short* __restrict__ u,
                                                  const float* __restrict__ xdbl,
                                                  const float* __restrict__ A_log,
                                                  float* __restrict__ P,
                                                  float* __restrict__ S) {
    int d = blockIdx.x * 256 + threadIdx.x;
    int c = blockIdx.y, b = blockIdx.z;
    __shared__ float bc[LC][16];
    int base_row = b * SEQ + c * LC;
    for (int e = threadIdx.x; e < LC * 16; e += 256) {
        int lrr = e >> 4, col = e & 15;
        bc[lrr][col] = xdbl[(size_t)(base_row + lrr) * XPAD + DT_RANK + col];
    }
    __syncthreads();
    float Ad[8];
    #pragma unroll
    for (int n = 0; n < 8; n++) Ad[n] = -__expf(A_log[d * 8 + n]);
    float prod[8], hs[8];
    #pragma unroll
    for (int n = 0; n < 8; n++) { prod[n] = 1.0f; hs[n] = 0.0f; }
    for (int lrr = 0; lrr < LC; lrr++) {
        int row = base_row + lrr;
        float dl = bf2f(delta[(size_t)row * D_INNER + d]);
        float uu = bf2f(u[(size_t)row * D_INNER + d]);
        float du = dl * uu;
        #pragma unroll
        for (int n = 0; n < 8; n++) {
            float dA = __expf(dl * Ad[n]);
            prod[n] *= dA;
            hs[n] = dA * hs[n] + du * bc[lrr][n];
        }
    }
    size_t o = ((size_t)((size_t)b * NC + c) * D_INNER + d) * 8;
    #pragma unroll
    for (int n = 0; n < 8; n++) { P[o + n] = prod[n]; S[o + n] = hs[n]; }
}

// ---------------- scan: pass B ----------------
__global__ __launch_bounds__(256) void scan_passB(const float* __restrict__ P,
                                                  const float* __restrict__ S,
                                                  float* __restrict__ hstart) {
    int tid = blockIdx.x * 256 + threadIdx.x;
    int b = tid / (D_INNER * 8);
    int rem = tid % (D_INNER * 8);
    float h = 0.0f;
    for (int c = 0; c < NC; c++) {
        size_t o = (size_t)(b * NC + c) * (D_INNER * 8) + rem;
        hstart[o] = h;
        h = P[o] * h + S[o];
    }
}

// ---------------- scan: pass C -> bf16 ygate ----------------
__global__ __launch_bounds__(256) void scan_passC(const unsigned short* __restrict__ delta,
                                                  const unsigned short* __restrict__ u,
                                                  const float* __restrict__ xdbl,
                                                  const float* __restrict__ A_log,
                                                  const float* __restrict__ hstart,
                                                  const unsigned short* __restrict__ xz,
                                                  const float* __restrict__ Dp,
                                                  unsigned short* __restrict__ ygate) {
    int d = blockIdx.x * 256 + threadIdx.x;
    int c = blockIdx.y, b = blockIdx.z;
    __shared__ float bc[LC][16];
    int base_row = b * SEQ + c * LC;
    for (int e = threadIdx.x; e < LC * 16; e += 256) {
        int lrr = e >> 4, col = e & 15;
        bc[lrr][col] = xdbl[(size_t)(base_row + lrr) * XPAD + DT_RANK + col];
    }
    __syncthreads();
    float Ad[8];
    #pragma unroll
    for (int n = 0; n < 8; n++) Ad[n] = -__expf(A_log[d * 8 + n]);
    float h[8];
    size_t ho = ((size_t)((size_t)b * NC + c) * D_INNER + d) * 8;
    #pragma unroll
    for (int n = 0; n < 8; n++) h[n] = hstart[ho + n];
    float Dd = Dp[d];
    for (int lrr = 0; lrr < LC; lrr++) {
        int row = base_row + lrr;
        float dl = bf2f(delta[(size_t)row * D_INNER + d]);
        float uu = bf2f(u[(size_t)row * D_INNER + d]);
        float du = dl * uu;
        float y = 0.0f;
        #pragma unroll
        for (int n = 0; n < 8; n++) {
            float dA = __expf(dl * Ad[n]);
            h[n] = dA * h[n] + du * bc[lrr][n];
            y += h[n] * bc[lrr][8 + n];
        }
        y += uu * Dd;
        float z = bf2f(xz[(size_t)row * (2 * D_INNER) + D_INNER + d]);
        ygate[(size_t)row * D_INNER + d] = f2bf(y * silu_f(z));
    }
}

// ---------------- launch ----------------
extern "C" void kernel_launch(void* const* d_in, const int* in_sizes, int n_in,
                              void* d_out, int out_size, void* d_ws, size_t ws_size,
                              hipStream_t stream) {
    const float* x         = (const float*)d_in[0];
    const float* ln1_g     = (const float*)d_in[1];
    const float* ln1_b     = (const float*)d_in[2];
    const float* ln2_g     = (const float*)d_in[3];
    const float* ln2_b     = (const float*)d_in[4];
    const float* in_proj_w = (const float*)d_in[5];
    const float* conv_w    = (const float*)d_in[6];
    const float* conv_b    = (const float*)d_in[7];
    const float* x_proj_w  = (const float*)d_in[8];
    const float* dt_proj_w = (const float*)d_in[9];
    const float* dt_proj_b = (const float*)d_in[10];
    const float* A_log     = (const float*)d_in[11];
    const float* Dp        = (const float*)d_in[12];
    const float* out_proj_w= (const float*)d_in[13];
    const float* ffn_w1    = (const float*)d_in[14];
    const float* ffn_b1    = (const float*)d_in[15];
    const float* ffn_w2    = (const float*)d_in[16];
    const float* ffn_b2    = (const float*)d_in[17];
    float* out = (float*)d_out;

    // ---- workspace layout ----
    float* xdbl  = (float*)d_ws;                           // 4096*128
    float* P     = xdbl + (size_t)NROWS * XPAD;
    float* S     = P + (size_t)BATCH * NC * D_INNER * 8;
    float* hst   = S + (size_t)BATCH * NC * D_INNER * 8;
    float* x2    = hst + (size_t)BATCH * NC * D_INNER * 8; // 4096*1024
    float* psumf = x2 + (size_t)NROWS * D_MODEL;           // 8M floats = 32MB region
    float* part  = psumf;                                  // overlay: x_proj splitK f32 partials (8MB)
    unsigned short* psum = (unsigned short*)psumf;         // scrambled bf16 partials (<=32MB)
    unsigned short* xz_bf   = (unsigned short*)(psumf + 2 * (size_t)NROWS * D_MODEL); // 4096*3072
    unsigned short* xp_bf   = xz_bf + (size_t)NROWS * 2 * D_INNER;   // 4096*1024 (reused as xn_bf)
    unsigned short* u_bf    = xp_bf + (size_t)NROWS * D_MODEL;       // 4096*1536
    unsigned short* xdbl_bf = u_bf + (size_t)NROWS * D_INNER;        // 4096*128
    unsigned short* yg_bf   = xdbl_bf + (size_t)NROWS * XPAD;        // 4096*1536
    unsigned short* dl_bf   = yg_bf + (size_t)NROWS * D_INNER;       // 4096*1536
    unsigned short* w_in    = dl_bf + (size_t)NROWS * D_INNER;       // 3072*1024
    unsigned short* w_xp    = w_in + (size_t)2 * D_INNER * D_MODEL;  // 128*1536
    unsigned short* w_dt    = w_xp + (size_t)XPAD * D_INNER;         // 1536*64
    unsigned short* w_out   = w_dt + (size_t)D_INNER * DT_RANK;      // 1024*1536
    unsigned short* w_f1    = w_out + (size_t)D_MODEL * D_INNER;     // 2048*1024
    unsigned short* w_f2    = w_f1 + (size_t)D_FF * D_MODEL;         // 1024*2048
    unsigned short* hff_bf  = xz_bf;   // overlay: xz dead after scan_passC

    // 0+1. prep: weight conversions + x_proj pad + LN1
    prep_kernel<<<4400 + XPAD + NROWS, 256, 0, stream>>>(
        in_proj_w, w_in, dt_proj_w, w_dt, out_proj_w, w_out, ffn_w1, w_f1, ffn_w2, w_f2,
        x_proj_w, w_xp, x, ln1_g, ln1_b, xp_bf);
    // 2. in_proj (4096 x 3072, K=1024) -> bf16 row-major  [8-phase 256x256]
    gemm8p<4, EPI_BF16, 1><<<dim3(3072 / 256, NROWS / 256), 512, 0, stream>>>(
        xp_bf, D_MODEL, w_in, D_MODEL, D_MODEL, nullptr, xz_bf, 2 * D_INNER, nullptr, nullptr, 0);
    // 3. conv + silu -> u (bf16)
    conv_silu<<<(NROWS * D_INNER) / (256 * 8), 256, 0, stream>>>(xz_bf, conv_w, conv_b, u_bf);
    // 4. x_proj split-K=4 (4096 x 128pad, K=384 each), f32 row-major partials
    gemm_mfma<EPI_F32, 4><<<dim3(1, NROWS / 128, 4), 256, 0, stream>>>(
        u_bf, D_INNER, w_xp, D_INNER, D_INNER / 4, part, nullptr, XPAD, nullptr, nullptr, 0);
    xdbl_reduce<<<(NROWS * XPAD) / 256, 256, 0, stream>>>(part, xdbl, xdbl_bf);
    // 5. dt_proj + softplus -> delta bf16 (4096 x 1536, K=64)
    gemm_mfma<EPI_SOFTPLUS_BF16, 1><<<dim3(D_INNER / 128, NROWS / 128), 256, 0, stream>>>(
        xdbl_bf, XPAD, w_dt, DT_RANK, DT_RANK, nullptr, dl_bf, D_INNER, dt_proj_b, nullptr, 0);
    // 6-8. selective scan
    scan_passA<<<dim3(D_INNER / 256, NC, BATCH), 256, 0, stream>>>(dl_bf, u_bf, xdbl, A_log, P, S);
    scan_passB<<<(BATCH * D_INNER * 8) / 256, 256, 0, stream>>>(P, S, hst);
    scan_passC<<<dim3(D_INNER / 256, NC, BATCH), 256, 0, stream>>>(dl_bf, u_bf, xdbl, A_log, hst, xz_bf, Dp, yg_bf);
    // 9. out_proj split-K=4 (K=384 each), scrambled bf16 psum  [WN=4, 256 blocks]
    gemm8p<4, EPI_SCR, 4><<<dim3(D_MODEL / 256, NROWS / 256, 4), 512, 0, stream>>>(
        yg_bf, D_INNER, w_out, D_INNER, D_INNER / 4, nullptr, psum, D_MODEL, nullptr, nullptr, 0);
    // 10. reduce+resid -> x2, then LN2 -> xn bf16
    skscr<0><<<(64 * 16384) / 256, 256, 0, stream>>>(psum, nullptr, x, x2, nullptr, 64, D_MODEL);
    ln_kernel<<<NROWS, 256, 0, stream>>>(x2, ln2_g, ln2_b, xp_bf);
    // 11. ffn1 split-K=2 (K=512 each), scrambled bf16 psum  [WN=4, 256 blocks]
    gemm8p<4, EPI_SCR, 2><<<dim3(D_FF / 256, NROWS / 256, 2), 512, 0, stream>>>(
        xp_bf, D_MODEL, w_f1, D_MODEL, D_MODEL / 2, nullptr, psum, D_FF, nullptr, nullptr, 0);
    // 12. reduce+bias+gelu -> hff bf16
    skscr<1><<<(128 * 16384) / 256, 256, 0, stream>>>(psum, ffn_b1, nullptr, nullptr, hff_bf, 128, D_FF);
    // 13. ffn2 split-K=4 (K=512 each), scrambled bf16 psum  [WN=4, 256 blocks]
    gemm8p<4, EPI_SCR, 4><<<dim3(D_MODEL / 256, NROWS / 256, 4), 512, 0, stream>>>(
        hff_bf, D_FF, w_f2, D_FF, D_FF / 4, nullptr, psum, D_MODEL, nullptr, nullptr, 0);
    // 14. reduce+bias+resid -> out
    skscr<2><<<(64 * 16384) / 256, 256, 0, stream>>>(psum, ffn_b2, x2, out, nullptr, 64, D_MODEL);
}

// Round 10
// 281.062 us; speedup vs baseline: 1.0327x; 1.0327x over previous
//
#include <hip/hip_runtime.h>
#include <math.h>

#define D_MODEL 1024
#define D_STATE 8
#define D_CONV  4
#define D_INNER 1536
#define DT_RANK 64
#define D_FF    2048
#define BATCH   2
#define SEQ     2048
#define NROWS   (BATCH*SEQ)      // 4096
#define NC      32               // scan chunks
#define LC      (SEQ/NC)         // 64
#define XPAD    128              // padded x_dbl width (was 80)

typedef short bf16x8 __attribute__((ext_vector_type(8)));
typedef unsigned short u16x8 __attribute__((ext_vector_type(8)));
typedef float f32x4  __attribute__((ext_vector_type(4)));

__device__ inline unsigned short f2bf(float x) {
    union { float f; unsigned u; } v; v.f = x;
    unsigned r = v.u + 0x7fffu + ((v.u >> 16) & 1u);
    return (unsigned short)(r >> 16);
}
__device__ inline float bf2f(unsigned short h) {
    union { unsigned u; float f; } v; v.u = ((unsigned)h) << 16;
    return v.f;
}
__device__ inline float softplus_f(float x) {
    return (x > 20.0f) ? x : log1pf(__expf(x));
}
__device__ inline float gelu_f(float x) {
    return 0.5f * x * (1.0f + erff(x * 0.70710678118654752f));
}
__device__ inline float silu_f(float x) {
    return x / (1.0f + __expf(-x));
}
__device__ inline void gload16(const unsigned short* g, unsigned short* l) {
    typedef unsigned int u32;
    __builtin_amdgcn_global_load_lds(
        (const __attribute__((address_space(1))) u32*)g,
        (__attribute__((address_space(3))) u32*)l, 16, 0, 0);
}

#define PHASE_SYNC_PRE()  do { __builtin_amdgcn_s_barrier(); \
                               asm volatile("s_waitcnt lgkmcnt(0)" ::: "memory"); } while (0)
#define PHASE_SYNC_POST() do { __builtin_amdgcn_s_barrier(); } while (0)

// ---------------- prep mega-kernel: weight conv + xproj pad + LN1 ----------------
__global__ __launch_bounds__(256) void prep_kernel(
    const float* __restrict__ s0, unsigned short* __restrict__ d0,
    const float* __restrict__ s1, unsigned short* __restrict__ d1,
    const float* __restrict__ s2, unsigned short* __restrict__ d2,
    const float* __restrict__ s3, unsigned short* __restrict__ d3,
    const float* __restrict__ s4, unsigned short* __restrict__ d4,
    const float* __restrict__ xpw, unsigned short* __restrict__ xpd,
    const float* __restrict__ x, const float* __restrict__ g1,
    const float* __restrict__ b1, unsigned short* __restrict__ xout) {
    int b = blockIdx.x;
    if (b < 4400) {
        const float* s; unsigned short* d; int base;
        if      (b < 1536) { s = s0; d = d0; base = b * 2048; }
        else if (b < 1584) { s = s1; d = d1; base = (b - 1536) * 2048; }
        else if (b < 2352) { s = s2; d = d2; base = (b - 1584) * 2048; }
        else if (b < 3376) { s = s3; d = d3; base = (b - 2352) * 2048; }
        else               { s = s4; d = d4; base = (b - 3376) * 2048; }
        int i = base + threadIdx.x * 8;
        float4 v0 = *(const float4*)(s + i);
        float4 v1 = *(const float4*)(s + i + 4);
        ushort4 a, c;
        a.x = f2bf(v0.x); a.y = f2bf(v0.y); a.z = f2bf(v0.z); a.w = f2bf(v0.w);
        c.x = f2bf(v1.x); c.y = f2bf(v1.y); c.z = f2bf(v1.z); c.w = f2bf(v1.w);
        *(ushort4*)(d + i)     = a;
        *(ushort4*)(d + i + 4) = c;
    } else if (b < 4528) {
        int row = b - 4400;
        for (int c = threadIdx.x; c < D_INNER; c += 256)
            xpd[row * D_INNER + c] = (row < 80) ? f2bf(xpw[row * D_INNER + c]) : (unsigned short)0;
    } else {
        __shared__ float sbuf[4];
        int row = b - 4528;
        int t = threadIdx.x;
        float4 v = ((const float4*)(x + (size_t)row * D_MODEL))[t];
        float s = v.x + v.y + v.z + v.w;
        for (int o = 32; o; o >>= 1) s += __shfl_down(s, o, 64);
        if ((t & 63) == 0) sbuf[t >> 6] = s;
        __syncthreads();
        float mu = (sbuf[0] + sbuf[1] + sbuf[2] + sbuf[3]) * (1.0f / D_MODEL);
        __syncthreads();
        float e0 = v.x - mu, e1 = v.y - mu, e2 = v.z - mu, e3 = v.w - mu;
        float q = e0*e0 + e1*e1 + e2*e2 + e3*e3;
        for (int o = 32; o; o >>= 1) q += __shfl_down(q, o, 64);
        if ((t & 63) == 0) sbuf[t >> 6] = q;
        __syncthreads();
        float var = (sbuf[0] + sbuf[1] + sbuf[2] + sbuf[3]) * (1.0f / D_MODEL);
        float rs = rsqrtf(var + 1e-5f);
        float4 gv = ((const float4*)g1)[t];
        float4 bv = ((const float4*)b1)[t];
        ushort4 st;
        st.x = f2bf(e0 * rs * gv.x + bv.x);
        st.y = f2bf(e1 * rs * gv.y + bv.y);
        st.z = f2bf(e2 * rs * gv.z + bv.z);
        st.w = f2bf(e3 * rs * gv.w + bv.w);
        ((ushort4*)(xout + (size_t)row * D_MODEL))[t] = st;
    }
}

// ---------------- LayerNorm -> bf16 ----------------
__global__ __launch_bounds__(256) void ln_kernel(const float* __restrict__ x,
                                                 const float* __restrict__ g,
                                                 const float* __restrict__ b,
                                                 unsigned short* __restrict__ out) {
    __shared__ float sbuf[4];
    int row = blockIdx.x;
    int t = threadIdx.x;
    float4 v = ((const float4*)(x + (size_t)row * D_MODEL))[t];
    float s = v.x + v.y + v.z + v.w;
    for (int o = 32; o; o >>= 1) s += __shfl_down(s, o, 64);
    if ((t & 63) == 0) sbuf[t >> 6] = s;
    __syncthreads();
    float mu = (sbuf[0] + sbuf[1] + sbuf[2] + sbuf[3]) * (1.0f / D_MODEL);
    __syncthreads();
    float d0 = v.x - mu, d1 = v.y - mu, d2 = v.z - mu, d3 = v.w - mu;
    float q = d0*d0 + d1*d1 + d2*d2 + d3*d3;
    for (int o = 32; o; o >>= 1) q += __shfl_down(q, o, 64);
    if ((t & 63) == 0) sbuf[t >> 6] = q;
    __syncthreads();
    float var = (sbuf[0] + sbuf[1] + sbuf[2] + sbuf[3]) * (1.0f / D_MODEL);
    float rs = rsqrtf(var + 1e-5f);
    float4 gv = ((const float4*)g)[t];
    float4 bv = ((const float4*)b)[t];
    ushort4 st;
    st.x = f2bf(d0 * rs * gv.x + bv.x);
    st.y = f2bf(d1 * rs * gv.y + bv.y);
    st.z = f2bf(d2 * rs * gv.z + bv.z);
    st.w = f2bf(d3 * rs * gv.w + bv.w);
    ((ushort4*)(out + (size_t)row * D_MODEL))[t] = st;
}

// ---------------- epilogue IDs ----------------
#define EPI_F32        0
#define EPI_F32_BF16   1
#define EPI_SOFTPLUS   2
#define EPI_RESID      3
#define EPI_GELU_BF16  4
#define EPI_BIAS_RESID 5
#define EPI_BF16       6
#define EPI_SOFTPLUS_BF16 7

// ================= 4-phase 256-row MFMA GEMM (NT) =================
// BM=256, BN=WN*64, BK=64, 8 waves, involution LDS swizzle byte^=(row&7)<<4,
// counted vmcnt at phases B/D, setprio around MFMA, XCD-aware block swizzle.
// Merged 4-phase schedule (32 MFMA/phase at WN=4): stage slots shifted so no
// phase ds_reads a region it also gload_lds-writes; ledger re-derived.
template<int WN, int EPI, int SPLITK>
__global__ __launch_bounds__(512, 2) void gemm8p(
    const unsigned short* __restrict__ A, int lda,
    const unsigned short* __restrict__ Bm, int ldb, int K,
    float* __restrict__ Cf, unsigned short* __restrict__ Cb, int ldc,
    const float* __restrict__ bias,
    const float* __restrict__ resid, int ldr) {
    constexpr int WM = 8 / WN;
    constexpr int BN = WN * 64;
    constexpr int RW = 256 / WM;
    constexpr int CW = 64;
    constexpr int MI = RW / 16;
    constexpr int NI = CW / 16;
    constexpr int MIH = MI / 2, NIH = NI / 2;
    constexpr int ABYTES = 256 * 128;
    constexpr int BBYTES = BN * 128;
    constexpr int BOFF = 2 * ABYTES;
    __shared__ unsigned short lds[(2 * ABYTES + 2 * BBYTES) / 2];

    const int t = threadIdx.x, l = t & 63, w = t >> 6;
    const int wr = w / WN, wc = w % WN;

    const int nx = gridDim.x;
    const int nwg = nx * gridDim.y;
    int bid = blockIdx.y * nx + blockIdx.x;
    int q = nwg >> 3;
    int swz = (bid & 7) * q + (bid >> 3);
    const int m0 = (swz / nx) * 256, n0 = (swz % nx) * BN;
    const int kbase = (SPLITK > 1) ? blockIdx.z * K : 0;

    // involution swizzle: LDS[r][byte] = G[r][byte ^ ((r&7)<<4)]
    const int sr = l >> 3;
    const int sj = ((l & 7) * 16) ^ ((l >> 3) << 4);
    const int row_l = w * 8;
    const int row_c = (w >> 2) * 64 + (w & 3) * 8;

    auto STG = [&](int bufbyte, int rowbase, const unsigned short* G, int ldg, int gbase, int kt) {
        unsigned short* dst = (unsigned short*)((char*)lds + bufbyte + rowbase * 128);
        const unsigned short* src = G + (size_t)(gbase + rowbase + sr) * ldg + kbase + kt * 64 + (sj >> 1);
        gload16(src, dst);
    };
    auto S_Ah0 = [&](int b, int kt) {
        if (WN == 4) { STG(b * ABYTES, row_l, A, lda, m0, kt);       STG(b * ABYTES, 128 + row_l, A, lda, m0, kt); }
        else         { STG(b * ABYTES, row_c, A, lda, m0, kt);       STG(b * ABYTES, 128 + row_c, A, lda, m0, kt); }
    };
    auto S_Ah1 = [&](int b, int kt) {
        if (WN == 4) { STG(b * ABYTES, 64 + row_l, A, lda, m0, kt);  STG(b * ABYTES, 192 + row_l, A, lda, m0, kt); }
        else         { STG(b * ABYTES, 32 + row_c, A, lda, m0, kt);  STG(b * ABYTES, 160 + row_c, A, lda, m0, kt); }
    };
    auto S_Bc0 = [&](int b, int kt) {
        if (WN == 4) { STG(BOFF + b * BBYTES, row_c, Bm, ldb, n0, kt); STG(BOFF + b * BBYTES, 128 + row_c, Bm, ldb, n0, kt); }
        else         { STG(BOFF + b * BBYTES, row_c, Bm, ldb, n0, kt); }
    };
    auto S_Bc1 = [&](int b, int kt) {
        if (WN == 4) { STG(BOFF + b * BBYTES, 32 + row_c, Bm, ldb, n0, kt); STG(BOFF + b * BBYTES, 160 + row_c, Bm, ldb, n0, kt); }
        else         { STG(BOFF + b * BBYTES, 32 + row_c, Bm, ldb, n0, kt); }
    };

    auto LD = [&](int bytebase, int row, int kb) -> bf16x8 {
        int o = bytebase + row * 128 + (kb ^ ((row & 7) << 4));
        return *(const bf16x8*)((const char*)lds + o);
    };

    f32x4 acc[MI][NI] = {};
    bf16x8 af[MIH][2], b0v[NIH][2], b1v[NIH][2];

    auto LDA_set = [&](int buf, int qr, auto& dst) {
        #pragma unroll
        for (int mi = 0; mi < MIH; mi++)
            #pragma unroll
            for (int ks = 0; ks < 2; ks++)
                dst[mi][ks] = LD(buf * ABYTES, wr * RW + qr * (RW / 2) + mi * 16 + (l & 15),
                                 ks * 64 + (l >> 4) * 16);
    };
    auto LDB_set = [&](int buf, int qc, auto& dst) {
        #pragma unroll
        for (int ni2 = 0; ni2 < NIH; ni2++)
            #pragma unroll
            for (int ks = 0; ks < 2; ks++)
                dst[ni2][ks] = LD(BOFF + buf * BBYTES, wc * CW + qc * 32 + ni2 * 16 + (l & 15),
                                  ks * 64 + (l >> 4) * 16);
    };
    auto MFMA_Q = [&](int qr, int qc, auto& a_, auto& b_) {
        __builtin_amdgcn_s_setprio(1);
        #pragma unroll
        for (int mi = 0; mi < MIH; mi++)
            #pragma unroll
            for (int ni2 = 0; ni2 < NIH; ni2++)
                #pragma unroll
                for (int ks = 0; ks < 2; ks++)
                    acc[qr * MIH + mi][qc * NIH + ni2] =
                        __builtin_amdgcn_mfma_f32_16x16x32_bf16(a_[mi][ks], b_[ni2][ks],
                                                                acc[qr * MIH + mi][qc * NIH + ni2], 0, 0, 0);
        __builtin_amdgcn_s_setprio(0);
    };
    // counted wait: drains loads issued >=1 phase earlier, leaves this phase's in flight
    auto VMW = [&](bool last) {
        if (last)            asm volatile("s_waitcnt vmcnt(0)" ::: "memory");
        else if (WN == 4)    asm volatile("s_waitcnt vmcnt(4)" ::: "memory");
        else                 asm volatile("s_waitcnt vmcnt(3)" ::: "memory");
    };

    const int ni_ = K >> 7;   // iterations; 2 K-tiles of 64 per iter

    // prologue: stage tiles 0,1 fully; wait for tile 0
    S_Ah0(0, 0); S_Ah1(0, 0); S_Bc0(0, 0); S_Bc1(0, 0);
    S_Ah0(1, 1); S_Ah1(1, 1); S_Bc0(1, 1); S_Bc1(1, 1);
    if (WN == 4) asm volatile("s_waitcnt vmcnt(8)" ::: "memory");
    else         asm volatile("s_waitcnt vmcnt(6)" ::: "memory");
    __builtin_amdgcn_s_barrier();

    for (int i = 0; i < ni_; i++) {
        const bool last = (i == ni_ - 1);
        const int t2 = 2 * i + 2, t3 = 2 * i + 3;
        // PA: buf0 quadrant-row 0  (stages buf1 tile 2i+1 remainder)
        LDA_set(0, 0, af); LDB_set(0, 0, b0v); LDB_set(0, 1, b1v);
        if (i) { S_Bc0(1, 2 * i + 1); S_Ah1(1, 2 * i + 1); }
        PHASE_SYNC_PRE();
        MFMA_Q(0, 0, af, b0v); MFMA_Q(0, 1, af, b1v);
        PHASE_SYNC_POST();
        // PB: buf0 quadrant-row 1
        LDA_set(0, 1, af);
        if (!last) { S_Ah0(0, t2); S_Bc1(0, t2); }
        VMW(last);
        PHASE_SYNC_PRE();
        MFMA_Q(1, 1, af, b1v); MFMA_Q(1, 0, af, b0v);
        PHASE_SYNC_POST();
        // PC: buf1 quadrant-row 0
        LDA_set(1, 0, af); LDB_set(1, 0, b0v); LDB_set(1, 1, b1v);
        if (!last) { S_Bc0(0, t2); S_Ah1(0, t2); }
        PHASE_SYNC_PRE();
        MFMA_Q(0, 0, af, b0v); MFMA_Q(0, 1, af, b1v);
        PHASE_SYNC_POST();
        // PD: buf1 quadrant-row 1
        LDA_set(1, 1, af);
        if (!last) { S_Ah0(1, t3); S_Bc1(1, t3); }
        VMW(last);
        PHASE_SYNC_PRE();
        MFMA_Q(1, 1, af, b1v); MFMA_Q(1, 0, af, b0v);
        PHASE_SYNC_POST();
    }

    float* Cfp = Cf;
    if (SPLITK > 1) Cfp += (size_t)blockIdx.z * NROWS * ldc;
    #pragma unroll
    for (int ni2 = 0; ni2 < NI; ni2++) {
        int col = n0 + wc * CW + ni2 * 16 + (l & 15);
        float bv = 0.0f;
        if (EPI == EPI_SOFTPLUS || EPI == EPI_GELU_BF16 || EPI == EPI_BIAS_RESID) bv = bias[col];
        #pragma unroll
        for (int mi = 0; mi < MI; mi++) {
            #pragma unroll
            for (int j = 0; j < 4; j++) {
                int row = m0 + wr * RW + mi * 16 + (l >> 4) * 4 + j;
                float v = acc[mi][ni2][j];
                if (EPI == EPI_SOFTPLUS)        v = softplus_f(v + bv);
                else if (EPI == EPI_GELU_BF16)  v = gelu_f(v + bv);
                else if (EPI == EPI_RESID)      v = v + resid[(size_t)row * ldr + col];
                else if (EPI == EPI_BIAS_RESID) v = v + bv + resid[(size_t)row * ldr + col];
                if (EPI == EPI_GELU_BF16 || EPI == EPI_BF16) {
                    Cb[(size_t)row * ldc + col] = f2bf(v);
                } else {
                    Cfp[(size_t)row * ldc + col] = v;
                    if (EPI == EPI_F32_BF16) Cb[(size_t)row * ldc + col] = f2bf(v);
                }
            }
        }
    }
}

// ---------------- fused split-K=2 reduce (+resid) + LayerNorm -> x2 f32, xn bf16 ----------------
__global__ __launch_bounds__(256) void sk2_ln(const float* __restrict__ p,
                                              const float* __restrict__ resid,
                                              const float* __restrict__ g,
                                              const float* __restrict__ b,
                                              float* __restrict__ x2,
                                              unsigned short* __restrict__ xn) {
    __shared__ float sbuf[4];
    int row = blockIdx.x;
    int t = threadIdx.x;
    const size_t seg = (size_t)NROWS * D_MODEL;
    size_t base = (size_t)row * D_MODEL + t * 4;
    float4 a = *(const float4*)(p + base);
    float4 bb = *(const float4*)(p + base + seg);
    float4 r = *(const float4*)(resid + base);
    float4 v;
    v.x = a.x + bb.x + r.x;
    v.y = a.y + bb.y + r.y;
    v.z = a.z + bb.z + r.z;
    v.w = a.w + bb.w + r.w;
    *(float4*)(x2 + base) = v;
    float s = v.x + v.y + v.z + v.w;
    for (int o = 32; o; o >>= 1) s += __shfl_down(s, o, 64);
    if ((t & 63) == 0) sbuf[t >> 6] = s;
    __syncthreads();
    float mu = (sbuf[0] + sbuf[1] + sbuf[2] + sbuf[3]) * (1.0f / D_MODEL);
    __syncthreads();
    float d0 = v.x - mu, d1 = v.y - mu, d2 = v.z - mu, d3 = v.w - mu;
    float qq = d0*d0 + d1*d1 + d2*d2 + d3*d3;
    for (int o = 32; o; o >>= 1) qq += __shfl_down(qq, o, 64);
    if ((t & 63) == 0) sbuf[t >> 6] = qq;
    __syncthreads();
    float var = (sbuf[0] + sbuf[1] + sbuf[2] + sbuf[3]) * (1.0f / D_MODEL);
    float rs = rsqrtf(var + 1e-5f);
    float4 gv = ((const float4*)g)[t];
    float4 bv = ((const float4*)b)[t];
    ushort4 st;
    st.x = f2bf(d0 * rs * gv.x + bv.x);
    st.y = f2bf(d1 * rs * gv.y + bv.y);
    st.z = f2bf(d2 * rs * gv.z + bv.z);
    st.w = f2bf(d3 * rs * gv.w + bv.w);
    ((ushort4*)(xn + (size_t)row * D_MODEL))[t] = st;
}

// ---------------- split-K=2 reduce + bias + resid (final output) ----------------
__global__ __launch_bounds__(256) void sk2_reduce(const float* __restrict__ p,
                                                  const float* __restrict__ bias,
                                                  const float* __restrict__ resid,
                                                  float* __restrict__ o) {
    int i = (blockIdx.x * 256 + threadIdx.x) * 4;
    const size_t seg = (size_t)NROWS * D_MODEL;
    float4 a = *(const float4*)(p + i);
    float4 b = *(const float4*)(p + i + seg);
    float4 r = *(const float4*)(resid + i);
    float4 bb = *(const float4*)(bias + (i & (D_MODEL - 1)));
    float4 o4;
    o4.x = a.x + b.x + r.x + bb.x;
    o4.y = a.y + b.y + r.y + bb.y;
    o4.z = a.z + b.z + r.z + bb.z;
    o4.w = a.w + b.w + r.w + bb.w;
    *(float4*)(o + i) = o4;
}

// ---------------- small-GEMM path (x_proj, dt_proj): 128x128, 3-buf ----------------
template<int EPI, int SPLITK>
__global__ __launch_bounds__(256) void gemm_mfma(
    const unsigned short* __restrict__ A, int lda,
    const unsigned short* __restrict__ B, int ldb, int K,
    float* __restrict__ Cf, unsigned short* __restrict__ Cb, int ldc,
    const float* __restrict__ bias,
    const float* __restrict__ resid, int ldr) {
    __shared__ unsigned short As[3][128 * 32];
    __shared__ unsigned short Bs[3][128 * 32];
    int t = threadIdx.x, l = t & 63, w = t >> 6;
    int nx = gridDim.x;
    int nwg = nx * gridDim.y;
    int bid = blockIdx.y * nx + blockIdx.x;
    int q = nwg >> 3;
    int swz = (bid & 7) * q + (bid >> 3);
    int m0 = (swz / nx) * 128, n0 = (swz % nx) * 128;
    int kbase = (SPLITK > 1) ? blockIdx.z * K : 0;
    int c0 = 2 * w, c1 = 2 * w + 1;
    int srow = l >> 2, scol = (l & 3) * 8;
    const unsigned short* Ag0 = A + (size_t)(m0 + 16 * c0 + srow) * lda + kbase + scol;
    const unsigned short* Ag1 = A + (size_t)(m0 + 16 * c1 + srow) * lda + kbase + scol;
    const unsigned short* Bg0 = B + (size_t)(n0 + 16 * c0 + srow) * ldb + kbase + scol;
    const unsigned short* Bg1 = B + (size_t)(n0 + 16 * c1 + srow) * ldb + kbase + scol;
    int wr = w >> 1, wc = w & 1;
    int aoff = (wr * 64 + (l & 15)) * 32 + (l >> 4) * 8;
    int boff = (wc * 64 + (l & 15)) * 32 + (l >> 4) * 8;

    f32x4 acc[4][4] = {};
    int nt = K >> 5;

    gload16(Ag0, &As[0][c0 * 512]);
    gload16(Ag1, &As[0][c1 * 512]);
    gload16(Bg0, &Bs[0][c0 * 512]);
    gload16(Bg1, &Bs[0][c1 * 512]);
    if (nt > 1) {
        gload16(Ag0 + 32, &As[1][c0 * 512]);
        gload16(Ag1 + 32, &As[1][c1 * 512]);
        gload16(Bg0 + 32, &Bs[1][c0 * 512]);
        gload16(Bg1 + 32, &Bs[1][c1 * 512]);
    }

    int cur = 0;
    for (int ti = 0; ti < nt; ti++) {
        int pf = ti + 2;
        if (pf < nt) {
            int nb = cur - 1; if (nb < 0) nb += 3;
            int k0 = pf << 5;
            gload16(Ag0 + k0, &As[nb][c0 * 512]);
            gload16(Ag1 + k0, &As[nb][c1 * 512]);
            gload16(Bg0 + k0, &Bs[nb][c0 * 512]);
            gload16(Bg1 + k0, &Bs[nb][c1 * 512]);
        }
        int rem = nt - 1 - ti;
        if (rem >= 2)      asm volatile("s_waitcnt vmcnt(8)" ::: "memory");
        else if (rem == 1) asm volatile("s_waitcnt vmcnt(4)" ::: "memory");
        else               asm volatile("s_waitcnt vmcnt(0)" ::: "memory");
        __builtin_amdgcn_s_barrier();

        const unsigned short* Ab = &As[cur][0];
        const unsigned short* Bb = &Bs[cur][0];
        bf16x8 af[4], bfv[4];
        #pragma unroll
        for (int i = 0; i < 4; i++) af[i] = *(const bf16x8*)(Ab + aoff + i * 512);
        #pragma unroll
        for (int i = 0; i < 4; i++) bfv[i] = *(const bf16x8*)(Bb + boff + i * 512);
        __builtin_amdgcn_s_setprio(1);
        #pragma unroll
        for (int mi = 0; mi < 4; mi++)
            #pragma unroll
            for (int ni = 0; ni < 4; ni++)
                acc[mi][ni] = __builtin_amdgcn_mfma_f32_16x16x32_bf16(af[mi], bfv[ni], acc[mi][ni], 0, 0, 0);
        __builtin_amdgcn_s_setprio(0);
        __builtin_amdgcn_s_barrier();
        cur++; if (cur == 3) cur = 0;
    }

    if (SPLITK > 1) Cf += (size_t)blockIdx.z * NROWS * ldc;
    int colb = n0 + wc * 64 + (l & 15);
    int rowb = m0 + wr * 64 + (l >> 4) * 4;
    #pragma unroll
    for (int ni = 0; ni < 4; ni++) {
        int col = colb + ni * 16;
        float bv = 0.0f;
        if (EPI == EPI_SOFTPLUS_BF16) bv = bias[col];
        #pragma unroll
        for (int mi = 0; mi < 4; mi++) {
            #pragma unroll
            for (int j = 0; j < 4; j++) {
                int row = rowb + mi * 16 + j;
                float v = acc[mi][ni][j];
                if (EPI == EPI_SOFTPLUS_BF16) v = softplus_f(v + bv);
                if (EPI == EPI_BF16 || EPI == EPI_SOFTPLUS_BF16) {
                    Cb[(size_t)row * ldc + col] = f2bf(v);
                } else {
                    Cf[(size_t)row * ldc + col] = v;
                }
            }
        }
    }
}

// ---------------- x_proj split-K partial reduce ----------------
__global__ __launch_bounds__(256) void xdbl_reduce(const float* __restrict__ part,
                                                   float* __restrict__ xdbl,
                                                   unsigned short* __restrict__ xdbl_bf) {
    int i = blockIdx.x * 256 + threadIdx.x;
    const size_t seg = (size_t)NROWS * XPAD;
    float s = part[i] + part[i + seg] + part[i + 2 * seg] + part[i + 3 * seg];
    xdbl[i] = s;
    xdbl_bf[i] = f2bf(s);
}

// ---------------- causal depthwise conv (k=4) + SiLU -> bf16 u (8-wide) ----------------
__global__ __launch_bounds__(256) void conv_silu(const unsigned short* __restrict__ xz,
                                                 const float* __restrict__ w,
                                                 const float* __restrict__ cb,
                                                 unsigned short* __restrict__ u) {
    int idx = (blockIdx.x * 256 + threadIdx.x) * 8;
    int d = idx % D_INNER;
    int bl = idx / D_INNER;
    int l = bl & (SEQ - 1);
    float acc[8];
    float4 wv[8];
    #pragma unroll
    for (int j = 0; j < 8; j++) wv[j] = *(const float4*)(w + (d + j) * 4);
    float4 cb0 = *(const float4*)(cb + d);
    float4 cb1 = *(const float4*)(cb + d + 4);
    acc[0] = cb0.x; acc[1] = cb0.y; acc[2] = cb0.z; acc[3] = cb0.w;
    acc[4] = cb1.x; acc[5] = cb1.y; acc[6] = cb1.z; acc[7] = cb1.w;
    #pragma unroll
    for (int k = 0; k < 4; k++) {
        int lp = l - 3 + k;
        if (lp >= 0) {
            u16x8 s = *(const u16x8*)(xz + (size_t)(bl - 3 + k) * (2 * D_INNER) + d);
            #pragma unroll
            for (int j = 0; j < 8; j++) {
                float wk = (k == 0) ? wv[j].x : (k == 1) ? wv[j].y : (k == 2) ? wv[j].z : wv[j].w;
                acc[j] += bf2f((unsigned short)s[j]) * wk;
            }
        }
    }
    u16x8 o;
    #pragma unroll
    for (int j = 0; j < 8; j++) o[j] = f2bf(silu_f(acc[j]));
    *(u16x8*)(u + idx) = o;
}

// ---------------- selective scan: pass A ----------------
__global__ __launch_bounds__(256) void scan_passA(const unsigned short* __restrict__ delta,
                                                  const unsigned short* __restrict__ u,
                                                  const float* __restrict__ xdbl,
                                                  const float* __restrict__ A_log,
                                                  float* __restrict__ P,
                                                  float* __restrict__ S) {
    int d = blockIdx.x * 256 + threadIdx.x;
    int c = blockIdx.y, b = blockIdx.z;
    __shared__ float bc[LC][16];
    int base_row = b * SEQ + c * LC;
    for (int e = threadIdx.x; e < LC * 16; e += 256) {
        int lrr = e >> 4, col = e & 15;
        bc[lrr][col] = xdbl[(size_t)(base_row + lrr) * XPAD + DT_RANK + col];
    }
    __syncthreads();
    float Ad[8];
    #pragma unroll
    for (int n = 0; n < 8; n++) Ad[n] = -__expf(A_log[d * 8 + n]);
    float prod[8], hs[8];
    #pragma unroll
    for (int n = 0; n < 8; n++) { prod[n] = 1.0f; hs[n] = 0.0f; }
    for (int lrr = 0; lrr < LC; lrr++) {
        int row = base_row + lrr;
        float dl = bf2f(delta[(size_t)row * D_INNER + d]);
        float uu = bf2f(u[(size_t)row * D_INNER + d]);
        float du = dl * uu;
        #pragma unroll
        for (int n = 0; n < 8; n++) {
            float dA = __expf(dl * Ad[n]);
            prod[n] *= dA;
            hs[n] = dA * hs[n] + du * bc[lrr][n];
        }
    }
    size_t o = ((size_t)((size_t)b * NC + c) * D_INNER + d) * 8;
    #pragma unroll
    for (int n = 0; n < 8; n++) { P[o + n] = prod[n]; S[o + n] = hs[n]; }
}

// ---------------- scan: pass B ----------------
__global__ __launch_bounds__(256) void scan_passB(const float* __restrict__ P,
                                                  const float* __restrict__ S,
                                                  float* __restrict__ hstart) {
    int tid = blockIdx.x * 256 + threadIdx.x;
    int b = tid / (D_INNER * 8);
    int rem = tid % (D_INNER * 8);
    float h = 0.0f;
    for (int c = 0; c < NC; c++) {
        size_t o = (size_t)(b * NC + c) * (D_INNER * 8) + rem;
        hstart[o] = h;
        h = P[o] * h + S[o];
    }
}

// ---------------- scan: pass C -> bf16 ygate ----------------
__global__ __launch_bounds__(256) void scan_passC(const unsigned short* __restrict__ delta,
                                                  const unsigned short* __restrict__ u,
                                                  const float* __restrict__ xdbl,
                                                  const float* __restrict__ A_log,
                                                  const float* __restrict__ hstart,
                                                  const unsigned short* __restrict__ xz,
                                                  const float* __restrict__ Dp,
                                                  unsigned short* __restrict__ ygate) {
    int d = blockIdx.x * 256 + threadIdx.x;
    int c = blockIdx.y, b = blockIdx.z;
    __shared__ float bc[LC][16];
    int base_row = b * SEQ + c * LC;
    for (int e = threadIdx.x; e < LC * 16; e += 256) {
        int lrr = e >> 4, col = e & 15;
        bc[lrr][col] = xdbl[(size_t)(base_row + lrr) * XPAD + DT_RANK + col];
    }
    __syncthreads();
    float Ad[8];
    #pragma unroll
    for (int n = 0; n < 8; n++) Ad[n] = -__expf(A_log[d * 8 + n]);
    float h[8];
    size_t ho = ((size_t)((size_t)b * NC + c) * D_INNER + d) * 8;
    #pragma unroll
    for (int n = 0; n < 8; n++) h[n] = hstart[ho + n];
    float Dd = Dp[d];
    for (int lrr = 0; lrr < LC; lrr++) {
        int row = base_row + lrr;
        float dl = bf2f(delta[(size_t)row * D_INNER + d]);
        float uu = bf2f(u[(size_t)row * D_INNER + d]);
        float du = dl * uu;
        float y = 0.0f;
        #pragma unroll
        for (int n = 0; n < 8; n++) {
            float dA = __expf(dl * Ad[n]);
            h[n] = dA * h[n] + du * bc[lrr][n];
            y += h[n] * bc[lrr][8 + n];
        }
        y += uu * Dd;
        float z = bf2f(xz[(size_t)row * (2 * D_INNER) + D_INNER + d]);
        ygate[(size_t)row * D_INNER + d] = f2bf(y * silu_f(z));
    }
}

// ---------------- launch ----------------
extern "C" void kernel_launch(void* const* d_in, const int* in_sizes, int n_in,
                              void* d_out, int out_size, void* d_ws, size_t ws_size,
                              hipStream_t stream) {
    const float* x         = (const float*)d_in[0];
    const float* ln1_g     = (const float*)d_in[1];
    const float* ln1_b     = (const float*)d_in[2];
    const float* ln2_g     = (const float*)d_in[3];
    const float* ln2_b     = (const float*)d_in[4];
    const float* in_proj_w = (const float*)d_in[5];
    const float* conv_w    = (const float*)d_in[6];
    const float* conv_b    = (const float*)d_in[7];
    const float* x_proj_w  = (const float*)d_in[8];
    const float* dt_proj_w = (const float*)d_in[9];
    const float* dt_proj_b = (const float*)d_in[10];
    const float* A_log     = (const float*)d_in[11];
    const float* Dp        = (const float*)d_in[12];
    const float* out_proj_w= (const float*)d_in[13];
    const float* ffn_w1    = (const float*)d_in[14];
    const float* ffn_b1    = (const float*)d_in[15];
    const float* ffn_w2    = (const float*)d_in[16];
    const float* ffn_b2    = (const float*)d_in[17];
    float* out = (float*)d_out;

    // ---- workspace layout ----
    float* xdbl  = (float*)d_ws;                           // 4096*128
    float* P     = xdbl + (size_t)NROWS * XPAD;
    float* S     = P + (size_t)BATCH * NC * D_INNER * 8;
    float* hst   = S + (size_t)BATCH * NC * D_INNER * 8;
    float* x2    = hst + (size_t)BATCH * NC * D_INNER * 8; // 4096*1024
    float* psum  = x2 + (size_t)NROWS * D_MODEL;           // 2*4096*1024 f32
    float* part  = psum;                                   // overlay: x_proj splitK partials
    unsigned short* xz_bf   = (unsigned short*)(psum + 2 * (size_t)NROWS * D_MODEL); // 4096*3072
    unsigned short* xp_bf   = xz_bf + (size_t)NROWS * 2 * D_INNER;   // 4096*1024 (reused as xn_bf)
    unsigned short* u_bf    = xp_bf + (size_t)NROWS * D_MODEL;       // 4096*1536
    unsigned short* xdbl_bf = u_bf + (size_t)NROWS * D_INNER;        // 4096*128
    unsigned short* yg_bf   = xdbl_bf + (size_t)NROWS * XPAD;        // 4096*1536
    unsigned short* dl_bf   = yg_bf + (size_t)NROWS * D_INNER;       // 4096*1536
    unsigned short* w_in    = dl_bf + (size_t)NROWS * D_INNER;       // 3072*1024
    unsigned short* w_xp    = w_in + (size_t)2 * D_INNER * D_MODEL;  // 128*1536
    unsigned short* w_dt    = w_xp + (size_t)XPAD * D_INNER;         // 1536*64
    unsigned short* w_out   = w_dt + (size_t)D_INNER * DT_RANK;      // 1024*1536
    unsigned short* w_f1    = w_out + (size_t)D_MODEL * D_INNER;     // 2048*1024
    unsigned short* w_f2    = w_f1 + (size_t)D_FF * D_MODEL;         // 1024*2048
    unsigned short* hff_bf  = xz_bf;   // overlay: xz dead after scan_passC

    // 0+1. prep: weight conversions + x_proj pad + LN1
    prep_kernel<<<4400 + XPAD + NROWS, 256, 0, stream>>>(
        in_proj_w, w_in, dt_proj_w, w_dt, out_proj_w, w_out, ffn_w1, w_f1, ffn_w2, w_f2,
        x_proj_w, w_xp, x, ln1_g, ln1_b, xp_bf);
    // 2. in_proj (4096 x 3072, K=1024) -> bf16   [4-phase 256x256]
    gemm8p<4, EPI_BF16, 1><<<dim3(3072 / 256, NROWS / 256), 512, 0, stream>>>(
        xp_bf, D_MODEL, w_in, D_MODEL, D_MODEL, nullptr, xz_bf, 2 * D_INNER, nullptr, nullptr, 0);
    // 3. conv + silu -> u (bf16)
    conv_silu<<<(NROWS * D_INNER) / (256 * 8), 256, 0, stream>>>(xz_bf, conv_w, conv_b, u_bf);
    // 4. x_proj split-K=4 (4096 x 128pad, K=384 each)
    gemm_mfma<EPI_F32, 4><<<dim3(1, NROWS / 128, 4), 256, 0, stream>>>(
        u_bf, D_INNER, w_xp, D_INNER, D_INNER / 4, part, nullptr, XPAD, nullptr, nullptr, 0);
    xdbl_reduce<<<(NROWS * XPAD) / 256, 256, 0, stream>>>(part, xdbl, xdbl_bf);
    // 5. dt_proj + softplus -> delta bf16 (4096 x 1536, K=64)
    gemm_mfma<EPI_SOFTPLUS_BF16, 1><<<dim3(D_INNER / 128, NROWS / 128), 256, 0, stream>>>(
        xdbl_bf, XPAD, w_dt, DT_RANK, DT_RANK, nullptr, dl_bf, D_INNER, dt_proj_b, nullptr, 0);
    // 6-8. selective scan
    scan_passA<<<dim3(D_INNER / 256, NC, BATCH), 256, 0, stream>>>(dl_bf, u_bf, xdbl, A_log, P, S);
    scan_passB<<<(BATCH * D_INNER * 8) / 256, 256, 0, stream>>>(P, S, hst);
    scan_passC<<<dim3(D_INNER / 256, NC, BATCH), 256, 0, stream>>>(dl_bf, u_bf, xdbl, A_log, hst, xz_bf, Dp, yg_bf);
    // 9. out_proj split-K=2 (4096 x 1024, K=768 each)  [4-phase 256x128, 256 blocks]
    gemm8p<2, EPI_F32, 2><<<dim3(D_MODEL / 128, NROWS / 256, 2), 512, 0, stream>>>(
        yg_bf, D_INNER, w_out, D_INNER, D_INNER / 2, psum, nullptr, D_MODEL, nullptr, nullptr, 0);
    // 10. fused reduce + residual + LN2 -> x2 f32, xn bf16
    sk2_ln<<<NROWS, 256, 0, stream>>>(psum, x, ln2_g, ln2_b, x2, xp_bf);
    // 11. ffn1 + gelu -> bf16 hff  (4096 x 2048, K=1024)  [4-phase 256x128, 256 blocks]
    gemm8p<2, EPI_GELU_BF16, 1><<<dim3(D_FF / 128, NROWS / 256), 512, 0, stream>>>(
        xp_bf, D_MODEL, w_f1, D_MODEL, D_MODEL, nullptr, hff_bf, D_FF, ffn_b1, nullptr, 0);
    // 12. ffn2 split-K=2 (4096 x 1024, K=1024 each)
    gemm8p<2, EPI_F32, 2><<<dim3(D_MODEL / 128, NROWS / 256, 2), 512, 0, stream>>>(
        hff_bf, D_FF, w_f2, D_FF, D_FF / 2, psum, nullptr, D_MODEL, nullptr, nullptr, 0);
    sk2_reduce<<<(NROWS * D_MODEL) / 1024, 256, 0, stream>>>(psum, ffn_b2, x2, out);
}